// Round 5
// baseline (9.976 us; speedup 1.0000x reference)
//
#include <hip/hip_runtime.h>
#include <math.h>

// BehlerG2 angular symmetry function, fused. FOUR rows per block (grid = 256
// blocks = 1 per CU), 512 threads. Tests the fixed-overhead-floor hypothesis:
// per-CU work identical to the 1-row/block variant, but 4x fewer block
// dispatches, 1 staging barrier instead of 4, and 32 KB of global loads
// batched in flight per block.
//
// Phase 1: thread tid computes triple tid of each of 4 rows -> LDS {r2, p}.
// Phase 2: 32 lane-groups of 16 (lane = eta e), 16 iters per row:
//   S[q][e,j] += exp(-r2 * eta_e) * (w * bs^{zeta_j})
// Epilogue: 512 threads write 4 rows x 128 outputs with c_z = 2^(1±zeta).

#define T_TRIP 512
#define ROWS 4
#define E_N 16

__global__ __launch_bounds__(512, 8) void behler_g2_kernel(
    const float* __restrict__ r_ij, const float* __restrict__ r_ik,
    const float* __restrict__ r_jk, const float* __restrict__ mask,
    const float* __restrict__ etas, const float* __restrict__ zetas,
    float* __restrict__ out)
{
    __shared__ float  R2s[ROWS][T_TRIP];      // r2 per triple per row
    __shared__ float4 Ps[ROWS][T_TRIP];       // w * bs^{zeta_j}
    __shared__ float  red[ROWS][8][E_N][4];   // per-wave partials per row

    const int blk = blockIdx.x;               // row group: rows 4*blk..4*blk+3
    const int tid = threadIdx.x;
    const size_t row0 = (size_t)blk * ROWS;

    const float z0 = zetas[0], z1 = zetas[1], z2 = zetas[2], z3 = zetas[3];
    const bool fastz = (z0 == 1.0f && z1 == 2.0f && z2 == 4.0f && z3 == 8.0f);
    const float PI_OVER_RC = 0.52359877559829887f;   // pi / 6

    // ---- Phase 1: batch all 16 loads, then per-triple scalar stage ----
    float a[ROWS], b[ROWS], c[ROWS], m[ROWS];
    #pragma unroll
    for (int q = 0; q < ROWS; ++q) {
        size_t idx = (row0 + q) * T_TRIP + tid;
        a[q] = r_ij[idx];
        b[q] = r_ik[idx];
        c[q] = r_jk[idx];
        m[q] = mask[idx];
    }
    #pragma unroll
    for (int q = 0; q < ROWS; ++q) {
        float r2 = fmaf(a[q], a[q], fmaf(b[q], b[q], c[q] * c[q]));
        float fa  = (a[q] < 6.0f) ? 0.5f * (__cosf(a[q] * PI_OVER_RC) + 1.0f) : 0.0f;
        float fb  = (b[q] < 6.0f) ? 0.5f * (__cosf(b[q] * PI_OVER_RC) + 1.0f) : 0.0f;
        float fcv = (c[q] < 6.0f) ? 0.5f * (__cosf(c[q] * PI_OVER_RC) + 1.0f) : 0.0f;
        float w = m[q] * fa * fb * fcv;
        float ct = __fdividef(r2, 2.0f * a[q] * b[q]);
        float4 p;
        if (fastz) {
            float bs = 1.0f - ct;             // w==0 annihilates any magnitude
            float s2 = bs * bs, s4 = s2 * s2, s8 = s4 * s4;
            p = make_float4(w * bs, w * s2, w * s4, w * s8);
        } else {
            if (m[q] == 0.0f) ct = 0.0f;      // powf(neg, frac) guard
            float bs = 1.0f - ct;
            p = make_float4(w * powf(bs, z0), w * powf(bs, z1),
                            w * powf(bs, z2), w * powf(bs, z3));
        }
        R2s[q][tid] = r2;
        Ps[q][tid] = p;
    }
    __syncthreads();

    // ---- Phase 2: 32 groups of 16 lanes; lane = eta index e ----
    const int g = tid >> 4;          // group 0..31, handles t == g (mod 32)
    const int e = tid & 15;
    const float me = -etas[e];
    const int wave = tid >> 6;       // 0..7

    #pragma unroll
    for (int q = 0; q < ROWS; ++q) {
        float acc0 = 0.0f, acc1 = 0.0f, acc2 = 0.0f, acc3 = 0.0f;
        #pragma unroll
        for (int i = 0; i < T_TRIP / 32; ++i) {
            int t = (i << 5) + g;
            float x = __expf(R2s[q][t] * me);   // broadcast b32 + mul + exp
            float4 p = Ps[q][t];                // broadcast b128
            acc0 = fmaf(x, p.x, acc0);
            acc1 = fmaf(x, p.y, acc1);
            acc2 = fmaf(x, p.z, acc2);
            acc3 = fmaf(x, p.w, acc3);
        }
        // reduce 4 groups within the wave (lanes l, l+16, l+32, l+48)
        acc0 += __shfl_down(acc0, 32); acc0 += __shfl_down(acc0, 16);
        acc1 += __shfl_down(acc1, 32); acc1 += __shfl_down(acc1, 16);
        acc2 += __shfl_down(acc2, 32); acc2 += __shfl_down(acc2, 16);
        acc3 += __shfl_down(acc3, 32); acc3 += __shfl_down(acc3, 16);
        if ((tid & 63) < 16) {
            red[q][wave][e][0] = acc0;
            red[q][wave][e][1] = acc1;
            red[q][wave][e][2] = acc2;
            red[q][wave][e][3] = acc3;
        }
    }
    __syncthreads();

    // ---- Epilogue: all 512 threads write 4 rows x 128 outputs ----
    {
        int q = tid >> 7, r = tid & 127;
        int ee = r >> 3, z = r & 7, j = z & 3;
        float s = 0.0f;
        #pragma unroll
        for (int wv = 0; wv < 8; ++wv) s += red[q][wv][ee][j];
        float zj = zetas[j];
        float coef = exp2f((z < 4) ? (1.0f - zj) : (1.0f + zj));
        out[(row0 + q) * 128 + r] = coef * s;
    }
}

extern "C" void kernel_launch(void* const* d_in, const int* in_sizes, int n_in,
                              void* d_out, int out_size, void* d_ws, size_t ws_size,
                              hipStream_t stream) {
    const float* r_ij = (const float*)d_in[0];
    const float* r_ik = (const float*)d_in[1];
    const float* r_jk = (const float*)d_in[2];
    const float* mask = (const float*)d_in[3];
    const float* etas = (const float*)d_in[4];
    const float* zetas = (const float*)d_in[5];
    float* out = (float*)d_out;

    int nblk = out_size / (128 * ROWS);   // 256 blocks, 4 rows each
    behler_g2_kernel<<<nblk, 512, 0, stream>>>(r_ij, r_ik, r_jk, mask,
                                               etas, zetas, out);
}